// Round 4
// baseline (103.910 us; speedup 1.0000x reference)
//
#include <hip/hip_runtime.h>
#include <math.h>

#define NN 8192
#define FF 128

typedef float f32x4 __attribute__((ext_vector_type(4)));

// Kernel 1: per-row dual dot product -> store exp(-(sL+b)) and exp(-sR).
// One wave (64 lanes) per row of x.
__global__ __launch_bounds__(256) void compute_s_kernel(
    const float* __restrict__ x,    // (N, F)
    const float* __restrict__ W,    // (2F,)
    const float* __restrict__ bptr, // scalar
    float* __restrict__ expL,       // (N,)  exp(-(x@wl + b))
    float* __restrict__ expR)       // (N,)  exp(-(x@wr))
{
    int gtid = blockIdx.x * blockDim.x + threadIdx.x;
    int row  = gtid >> 6;           // one 64-lane wave per row
    int lane = threadIdx.x & 63;
    if (row >= NN) return;

    const float2 xv = *reinterpret_cast<const float2*>(x + (size_t)row * FF + 2 * lane);
    const float2 wl = *reinterpret_cast<const float2*>(W + 2 * lane);
    const float2 wr = *reinterpret_cast<const float2*>(W + FF + 2 * lane);

    float accL = xv.x * wl.x + xv.y * wl.y;
    float accR = xv.x * wr.x + xv.y * wr.y;

    #pragma unroll
    for (int off = 32; off > 0; off >>= 1) {
        accL += __shfl_xor(accL, off, 64);
        accR += __shfl_xor(accR, off, 64);
    }
    if (lane == 0) {
        expL[row] = __expf(-(accL + *bptr));
        expR[row] = __expf(-accR);
    }
}

// Kernel 2: two rows per block.
// out[i][j] = adj[i][j] * rcp(1 + expL[i]*expR[j])
__global__ __launch_bounds__(256) void dense_att_row2_kernel(
    const float* __restrict__ adj,
    const float* __restrict__ expL,
    const float* __restrict__ expR,
    float* __restrict__ out)
{
    const int row0 = blockIdx.x * 2;
    const int row1 = row0 + 1;
    const int tid  = threadIdx.x;

    const f32x4* __restrict__ adj0 = reinterpret_cast<const f32x4*>(adj) + (size_t)row0 * (NN / 4);
    const f32x4* __restrict__ adj1 = reinterpret_cast<const f32x4*>(adj) + (size_t)row1 * (NN / 4);
    const f32x4* __restrict__ eR4  = reinterpret_cast<const f32x4*>(expR);
    f32x4* __restrict__ out0       = reinterpret_cast<f32x4*>(out) + (size_t)row0 * (NN / 4);
    f32x4* __restrict__ out1       = reinterpret_cast<f32x4*>(out) + (size_t)row1 * (NN / 4);

    const float eL0 = expL[row0];
    const float eL1 = expL[row1];

    f32x4 a0[8], a1[8], r[8];
    // Issue all loads first — 24 outstanding 16B loads per lane.
    #pragma unroll
    for (int k = 0; k < 8; ++k)
        a0[k] = __builtin_nontemporal_load(&adj0[tid + 256 * k]);   // streaming
    #pragma unroll
    for (int k = 0; k < 8; ++k)
        a1[k] = __builtin_nontemporal_load(&adj1[tid + 256 * k]);   // streaming
    #pragma unroll
    for (int k = 0; k < 8; ++k)
        r[k] = eR4[tid + 256 * k];                                   // L2-resident, reused 2x

    #pragma unroll
    for (int k = 0; k < 8; ++k) {
        f32x4 o;
        o.x = a0[k].x * __builtin_amdgcn_rcpf(1.0f + eL0 * r[k].x);
        o.y = a0[k].y * __builtin_amdgcn_rcpf(1.0f + eL0 * r[k].y);
        o.z = a0[k].z * __builtin_amdgcn_rcpf(1.0f + eL0 * r[k].z);
        o.w = a0[k].w * __builtin_amdgcn_rcpf(1.0f + eL0 * r[k].w);
        __builtin_nontemporal_store(o, &out0[tid + 256 * k]);
    }
    #pragma unroll
    for (int k = 0; k < 8; ++k) {
        f32x4 o;
        o.x = a1[k].x * __builtin_amdgcn_rcpf(1.0f + eL1 * r[k].x);
        o.y = a1[k].y * __builtin_amdgcn_rcpf(1.0f + eL1 * r[k].y);
        o.z = a1[k].z * __builtin_amdgcn_rcpf(1.0f + eL1 * r[k].z);
        o.w = a1[k].w * __builtin_amdgcn_rcpf(1.0f + eL1 * r[k].w);
        __builtin_nontemporal_store(o, &out1[tid + 256 * k]);
    }
}

extern "C" void kernel_launch(void* const* d_in, const int* in_sizes, int n_in,
                              void* d_out, int out_size, void* d_ws, size_t ws_size,
                              hipStream_t stream) {
    const float* x   = (const float*)d_in[0];   // (8192, 128)
    const float* adj = (const float*)d_in[1];   // (8192, 8192)
    const float* W   = (const float*)d_in[2];   // (256,)
    const float* b   = (const float*)d_in[3];   // scalar (1-elem device array)
    float* out = (float*)d_out;

    float* expL = (float*)d_ws;                 // 8192 floats
    float* expR = expL + NN;                    // 8192 floats

    compute_s_kernel<<<NN / 4, 256, 0, stream>>>(x, W, b, expL, expR);
    dense_att_row2_kernel<<<NN / 2, 256, 0, stream>>>(adj, expL, expR, out);
}

// Round 5
// 96.860 us; speedup vs baseline: 1.0728x; 1.0728x over previous
//
#include <hip/hip_runtime.h>
#include <math.h>

#define NN 8192
#define FF 128

typedef float f32x4 __attribute__((ext_vector_type(4)));

// Kernel 1: per-row dual dot product -> store exp(-(sL+b)) and exp(-sR).
// One wave (64 lanes) per row of x.
__global__ __launch_bounds__(256) void compute_s_kernel(
    const float* __restrict__ x,    // (N, F)
    const float* __restrict__ W,    // (2F,)
    const float* __restrict__ bptr, // scalar
    float* __restrict__ expL,       // (N,)  exp(-(x@wl + b))
    float* __restrict__ expR)       // (N,)  exp(-(x@wr))
{
    int gtid = blockIdx.x * blockDim.x + threadIdx.x;
    int row  = gtid >> 6;           // one 64-lane wave per row
    int lane = threadIdx.x & 63;
    if (row >= NN) return;

    const float2 xv = *reinterpret_cast<const float2*>(x + (size_t)row * FF + 2 * lane);
    const float2 wl = *reinterpret_cast<const float2*>(W + 2 * lane);
    const float2 wr = *reinterpret_cast<const float2*>(W + FF + 2 * lane);

    float accL = xv.x * wl.x + xv.y * wl.y;
    float accR = xv.x * wr.x + xv.y * wr.y;

    #pragma unroll
    for (int off = 32; off > 0; off >>= 1) {
        accL += __shfl_xor(accL, off, 64);
        accR += __shfl_xor(accR, off, 64);
    }
    if (lane == 0) {
        expL[row] = __expf(-(accL + *bptr));
        expR[row] = __expf(-accR);
    }
}

// Kernel 2: one row per block (R3 structure — best occupancy).
// out[i][j] = adj[i][j] * rcp(1 + expL[i]*expR[j])  — no exp in inner loop.
__global__ __launch_bounds__(256) void dense_att_row_kernel(
    const float* __restrict__ adj,
    const float* __restrict__ expL,
    const float* __restrict__ expR,
    float* __restrict__ out)
{
    const int row = blockIdx.x;
    const int tid = threadIdx.x;

    const f32x4* __restrict__ adjr = reinterpret_cast<const f32x4*>(adj) + (size_t)row * (NN / 4);
    const f32x4* __restrict__ eR4  = reinterpret_cast<const f32x4*>(expR);
    f32x4* __restrict__ outr       = reinterpret_cast<f32x4*>(out) + (size_t)row * (NN / 4);

    const float eL = expL[row];

    f32x4 a[8], r[8];
    // Issue all 16 loads first — deep MLP, no dependent address math.
    #pragma unroll
    for (int k = 0; k < 8; ++k)
        a[k] = __builtin_nontemporal_load(&adjr[tid + 256 * k]);   // streaming
    #pragma unroll
    for (int k = 0; k < 8; ++k)
        r[k] = eR4[tid + 256 * k];                                  // L2-resident

    #pragma unroll
    for (int k = 0; k < 8; ++k) {
        f32x4 o;
        o.x = a[k].x * __builtin_amdgcn_rcpf(1.0f + eL * r[k].x);
        o.y = a[k].y * __builtin_amdgcn_rcpf(1.0f + eL * r[k].y);
        o.z = a[k].z * __builtin_amdgcn_rcpf(1.0f + eL * r[k].z);
        o.w = a[k].w * __builtin_amdgcn_rcpf(1.0f + eL * r[k].w);
        __builtin_nontemporal_store(o, &outr[tid + 256 * k]);       // stream out
    }
}

extern "C" void kernel_launch(void* const* d_in, const int* in_sizes, int n_in,
                              void* d_out, int out_size, void* d_ws, size_t ws_size,
                              hipStream_t stream) {
    const float* x   = (const float*)d_in[0];   // (8192, 128)
    const float* adj = (const float*)d_in[1];   // (8192, 8192)
    const float* W   = (const float*)d_in[2];   // (256,)
    const float* b   = (const float*)d_in[3];   // scalar (1-elem device array)
    float* out = (float*)d_out;

    float* expL = (float*)d_ws;                 // 8192 floats
    float* expR = expL + NN;                    // 8192 floats

    compute_s_kernel<<<NN / 4, 256, 0, stream>>>(x, W, b, expL, expR);
    dense_att_row_kernel<<<NN, 256, 0, stream>>>(adj, expL, expR, out);
}